// Round 2
// baseline (9483.324 us; speedup 1.0000x reference)
//
#include <hip/hip_runtime.h>
#include <math.h>

typedef unsigned short u16;
typedef __attribute__((ext_vector_type(8))) short short8;
typedef __attribute__((ext_vector_type(4))) float f32x4;

#define LAYERS 8
#define D 1024
#define NH 16
#define DKH 64
#define DFF 4096
#define SEQ 66
#define TT 67
#define BATCH 256
#define ROWS (BATCH*TT)   /* 17152 = 134*128 */
#define VOCAB 4096

__device__ __forceinline__ float bf2f(u16 v){
  unsigned int u = ((unsigned int)v) << 16;
  return __builtin_bit_cast(float, u);
}
__device__ __forceinline__ u16 f2bf(float f){
  unsigned int u = __builtin_bit_cast(unsigned int, f);
  u += 0x7FFFu + ((u >> 16) & 1u);
  return (u16)(u >> 16);
}

// ---------------- transpose + cast f32 -> bf16 ----------------
// src: R x C (f32), dst: C x R (bf16)
__global__ void transpose_cast(const float* __restrict__ src, u16* __restrict__ dst,
                               int R, int C){
  __shared__ float tile[32][33];
  const int c0 = blockIdx.x * 32, r0 = blockIdx.y * 32;
  const int tx = threadIdx.x, ty = threadIdx.y;
  #pragma unroll
  for (int i = 0; i < 32; i += 8)
    tile[ty + i][tx] = src[(size_t)(r0 + ty + i) * C + (c0 + tx)];
  __syncthreads();
  #pragma unroll
  for (int i = 0; i < 32; i += 8)
    dst[(size_t)(c0 + ty + i) * R + (r0 + tx)] = f2bf(tile[tx][ty + i]);
}

// ---------------- embedding + positional encoding ----------------
__global__ void embed_kernel(const int* __restrict__ x, const float* __restrict__ emb,
                             const float* __restrict__ pool, float* __restrict__ h,
                             u16* __restrict__ hb){
  const int row = blockIdx.x;
  const int b = row / TT, t = row % TT;
  const int d0 = threadIdx.x * 4;
  float v[4];
  if (t == 0){
    const float4 p4 = *(const float4*)&pool[d0];
    v[0] = p4.x; v[1] = p4.y; v[2] = p4.z; v[3] = p4.w;
  } else {
    const int id = x[b * SEQ + (t - 1)];
    const float4 e4 = *(const float4*)&emb[(size_t)id * D + d0];
    v[0] = e4.x * 32.f; v[1] = e4.y * 32.f; v[2] = e4.z * 32.f; v[3] = e4.w * 32.f;
  }
  const float c = -logf(10000.f) / (float)D;
  float o[4];
  #pragma unroll
  for (int j = 0; j < 4; j++){
    const int d = d0 + j;
    const int p = d >> 1;
    const float freq = expf((float)(2 * p) * c);
    const float ang = (float)t * freq;
    const float pe = (d & 1) ? cosf(ang) : sinf(ang);
    o[j] = v[j] + pe;
  }
  *(float4*)&h[(size_t)row * D + d0] = make_float4(o[0], o[1], o[2], o[3]);
  const unsigned int lo = (unsigned)f2bf(o[0]) | ((unsigned)f2bf(o[1]) << 16);
  const unsigned int hi = (unsigned)f2bf(o[2]) | ((unsigned)f2bf(o[3]) << 16);
  *(uint2*)&hb[(size_t)row * D + d0] = make_uint2(lo, hi);
}

// ---------------- fused residual + LayerNorm (writes f32 stream + bf16 copy) ----------------
__global__ void ln_kernel(float* __restrict__ h, const float* __restrict__ res,
                          u16* __restrict__ hb, const float* __restrict__ g,
                          const float* __restrict__ bta){
  const int row = blockIdx.x;
  const int tid = threadIdx.x;
  const size_t off = (size_t)row * D + tid * 4;
  const float4 a = *(const float4*)&h[off];
  const float4 r4 = *(const float4*)&res[off];
  const float s0 = a.x + r4.x, s1 = a.y + r4.y, s2 = a.z + r4.z, s3 = a.w + r4.w;
  float sum = s0 + s1 + s2 + s3;
  float sq = s0*s0 + s1*s1 + s2*s2 + s3*s3;
  #pragma unroll
  for (int m = 32; m >= 1; m >>= 1){ sum += __shfl_xor(sum, m); sq += __shfl_xor(sq, m); }
  __shared__ float red[2][4];
  const int w = tid >> 6;
  if ((tid & 63) == 0){ red[0][w] = sum; red[1][w] = sq; }
  __syncthreads();
  sum = red[0][0] + red[0][1] + red[0][2] + red[0][3];
  sq  = red[1][0] + red[1][1] + red[1][2] + red[1][3];
  const float mean = sum * (1.f / D);
  const float var = sq * (1.f / D) - mean * mean;
  const float rs = rsqrtf(var + 1e-5f);
  const float4 gv = *(const float4*)&g[tid * 4];
  const float4 bv = *(const float4*)&bta[tid * 4];
  const float o0 = (s0 - mean) * rs * gv.x + bv.x;
  const float o1 = (s1 - mean) * rs * gv.y + bv.y;
  const float o2 = (s2 - mean) * rs * gv.z + bv.z;
  const float o3 = (s3 - mean) * rs * gv.w + bv.w;
  *(float4*)&h[off] = make_float4(o0, o1, o2, o3);
  const unsigned int lo = (unsigned)f2bf(o0) | ((unsigned)f2bf(o1) << 16);
  const unsigned int hi = (unsigned)f2bf(o2) | ((unsigned)f2bf(o3) << 16);
  *(uint2*)&hb[off] = make_uint2(lo, hi);
}

// ---------------- attention: one block per (batch, head) ----------------
__global__ __launch_bounds__(256) void attn_kernel(const u16* __restrict__ qb,
    const u16* __restrict__ kb, const u16* __restrict__ vb,
    const float* __restrict__ rel, u16* __restrict__ ctxb){
  __shared__ float K_s[TT][65];
  __shared__ float V_s[TT][65];
  __shared__ float qrow[4][64];
  __shared__ float p_s[4][68];
  const int bh = blockIdx.x;
  const int b = bh >> 4, hh = bh & 15;
  const int tid = threadIdx.x, w = tid >> 6, l = tid & 63;
  const size_t rowbase = (size_t)(b * TT) * D + hh * DKH;
  for (int idx = tid; idx < TT * 64; idx += 256){
    const int j = idx >> 6, d = idx & 63;
    K_s[j][d] = bf2f(kb[rowbase + (size_t)j * D + d]);
    V_s[j][d] = bf2f(vb[rowbase + (size_t)j * D + d]);
  }
  __syncthreads();
  for (int i = w; i < TT; i += 4){
    qrow[w][l] = bf2f(qb[rowbase + (size_t)i * D + l]);
    asm volatile("s_waitcnt lgkmcnt(0)" ::: "memory");
    const int j2 = 64 + (l < 3 ? l : 2);
    float s1 = 0.f, s2 = 0.f;
    #pragma unroll 8
    for (int d = 0; d < 64; ++d){
      const float qd = qrow[w][d];
      s1 += qd * K_s[l][d];
      s2 += qd * K_s[j2][d];
    }
    const float* relrow = rel + ((size_t)hh * 78 + i) * 78;
    float sc1 = s1 * 0.125f + relrow[l];
    float sc2 = (l < 3) ? (s2 * 0.125f + relrow[64 + l]) : -1e30f;
    float mx = fmaxf(sc1, sc2);
    #pragma unroll
    for (int m = 32; m >= 1; m >>= 1) mx = fmaxf(mx, __shfl_xor(mx, m));
    const float e1 = __expf(sc1 - mx);
    const float e2 = (l < 3) ? __expf(sc2 - mx) : 0.f;
    float sumv = e1 + e2;
    #pragma unroll
    for (int m = 32; m >= 1; m >>= 1) sumv += __shfl_xor(sumv, m);
    p_s[w][l] = e1;
    if (l < 3) p_s[w][64 + l] = e2;
    asm volatile("s_waitcnt lgkmcnt(0)" ::: "memory");
    const float inv = 1.f / sumv;
    float acc = 0.f;
    #pragma unroll 8
    for (int j = 0; j < TT; ++j) acc += p_s[w][j] * V_s[j][l];
    ctxb[rowbase + (size_t)i * D + l] = f2bf(acc * inv);
  }
}

// ---------------- bf16 MFMA GEMM (reg-staged): C = A @ Bt^T (+bias)(+gelu) ----------------
// A: M x K bf16 (row stride lda), Bt: N x K bf16 (row stride K), C: M x N
template<int OBF16, int BIAS, int GELU>
__global__ __launch_bounds__(256, 2) void gemm_bt(
    const u16* __restrict__ A, int lda,
    const u16* __restrict__ Bt,
    void* __restrict__ Cv, int ldc,
    const float* __restrict__ bias, int K)
{
  __shared__ u16 As[128 * 32];
  __shared__ u16 Bs[128 * 32];
  const int m0 = blockIdx.x * 128, n0 = blockIdx.y * 128;
  const int tid = threadIdx.x;
  const int l = tid & 63, w = tid >> 6;
  const int wr = w >> 1, wc = w & 1;
  // staging: thread covers 2 A-rows and 2 B-rows, 8 elems (16B) each
  const int srow = tid >> 2;        // 0..63
  const int sseg = (tid & 3) * 8;   // 0,8,16,24
  const u16* gA0 = A + (size_t)(m0 + srow) * lda + sseg;
  const u16* gA1 = A + (size_t)(m0 + 64 + srow) * lda + sseg;
  const u16* gB0 = Bt + (size_t)(n0 + srow) * K + sseg;
  const u16* gB1 = Bt + (size_t)(n0 + 64 + srow) * K + sseg;
  u16* sA0 = &As[srow * 32 + sseg];
  u16* sA1 = &As[(64 + srow) * 32 + sseg];
  u16* sB0 = &Bs[srow * 32 + sseg];
  u16* sB1 = &Bs[(64 + srow) * 32 + sseg];
  f32x4 acc[4][4] = {};
  const int fr = l & 15, kg = (l >> 4) * 8;
  for (int kt = 0; kt < K; kt += 32){
    const short8 a0 = *(const short8*)(gA0 + kt);
    const short8 a1 = *(const short8*)(gA1 + kt);
    const short8 b0 = *(const short8*)(gB0 + kt);
    const short8 b1 = *(const short8*)(gB1 + kt);
    __syncthreads();                      // previous tile fully consumed
    *(short8*)sA0 = a0; *(short8*)sA1 = a1;
    *(short8*)sB0 = b0; *(short8*)sB1 = b1;
    __syncthreads();
    short8 af[4], bf[4];
    #pragma unroll
    for (int i = 0; i < 4; i++){
      af[i] = *(const short8*)&As[(wr * 64 + i * 16 + fr) * 32 + kg];
      bf[i] = *(const short8*)&Bs[(wc * 64 + i * 16 + fr) * 32 + kg];
    }
    #pragma unroll
    for (int i = 0; i < 4; i++)
      #pragma unroll
      for (int j = 0; j < 4; j++)
        acc[i][j] = __builtin_amdgcn_mfma_f32_16x16x32_bf16(af[i], bf[j], acc[i][j], 0, 0, 0);
  }
  const int rg = (l >> 4) * 4;
  #pragma unroll
  for (int i = 0; i < 4; i++){
    #pragma unroll
    for (int j = 0; j < 4; j++){
      const int col = n0 + wc * 64 + j * 16 + fr;
      const float bv = BIAS ? bias[col] : 0.f;
      #pragma unroll
      for (int r = 0; r < 4; r++){
        const int row = m0 + wr * 64 + i * 16 + rg + r;
        float xv = acc[i][j][r] + bv;
        if (GELU) xv = 0.5f * xv * (1.f + erff(xv * 0.70710678118f));
        if (OBF16) ((u16*)Cv)[(size_t)row * ldc + col] = f2bf(xv);
        else       ((float*)Cv)[(size_t)row * ldc + col] = xv;
      }
    }
  }
}

extern "C" void kernel_launch(void* const* d_in, const int* in_sizes, int n_in,
                              void* d_out, int out_size, void* d_ws, size_t ws_size,
                              hipStream_t stream) {
  const int*   x       = (const int*)  d_in[0];
  const float* emb     = (const float*)d_in[1];
  const float* pool    = (const float*)d_in[2];
  const float* Wq      = (const float*)d_in[3];
  const float* Wk      = (const float*)d_in[4];
  const float* Wv      = (const float*)d_in[5];
  const float* Wo      = (const float*)d_in[6];
  const float* rel     = (const float*)d_in[7];
  const float* ln1_g   = (const float*)d_in[8];
  const float* ln1_b   = (const float*)d_in[9];
  const float* ln2_g   = (const float*)d_in[10];
  const float* ln2_b   = (const float*)d_in[11];
  const float* W1      = (const float*)d_in[12];
  const float* b1      = (const float*)d_in[13];
  const float* W2      = (const float*)d_in[14];
  const float* b2      = (const float*)d_in[15];
  const float* Wout    = (const float*)d_in[16];
  const float* bout    = (const float*)d_in[17];
  float* out = (float*)d_out;

  // ---- workspace layout (~350 MB) ----
  const size_t SZ_WDD  = (size_t)D * D * 2;        //  2 MB, per-layer reuse
  const size_t SZ_WDF  = (size_t)D * DFF * 2;      //  8 MB, per-layer reuse
  const size_t SZ_H    = (size_t)ROWS * D * 4;     // 70.3 MB
  const size_t SZ_HB   = (size_t)ROWS * D * 2;     // 35.1 MB
  const size_t need = 4*SZ_WDD + 3*SZ_WDF + SZ_H + SZ_HB + 4*SZ_HB + SZ_H;
  if (ws_size < need) return;   // zero-output signature => ws too small

  char* p = (char*)d_ws;
  u16* WqT  = (u16*)p; p += SZ_WDD;
  u16* WkT  = (u16*)p; p += SZ_WDD;
  u16* WvT  = (u16*)p; p += SZ_WDD;
  u16* WoT  = (u16*)p; p += SZ_WDD;
  u16* W1T  = (u16*)p; p += SZ_WDF;
  u16* W2T  = (u16*)p; p += SZ_WDF;
  u16* WouT = (u16*)p; p += SZ_WDF;
  float* h  = (float*)p; p += SZ_H;
  u16* hb   = (u16*)p; p += SZ_HB;
  u16* qb   = (u16*)p; p += SZ_HB;
  u16* kb   = (u16*)p; p += SZ_HB;
  u16* vb   = (u16*)p; p += SZ_HB;
  u16* ctxb = (u16*)p; p += SZ_HB;
  u16* gb   = qb;                 // FFN hidden aliases q/k/v/ctx (exactly 4*SZ_HB)
  float* tmp = (float*)p; p += SZ_H;   // residual-branch f32, NO aliasing

  dim3 tb(32, 8);
  transpose_cast<<<dim3(VOCAB/32, D/32), tb, 0, stream>>>(Wout, WouT, D, VOCAB);
  embed_kernel<<<ROWS, 256, 0, stream>>>(x, emb, pool, h, hb);

  const dim3 gDD(ROWS/128, D/128);
  const dim3 gDF(ROWS/128, DFF/128);
  for (int l = 0; l < LAYERS; ++l){
    const size_t wo = (size_t)l * D * D;
    const size_t wf = (size_t)l * D * DFF;
    transpose_cast<<<dim3(D/32,   D/32),   tb, 0, stream>>>(Wq + wo, WqT, D, D);
    transpose_cast<<<dim3(D/32,   D/32),   tb, 0, stream>>>(Wk + wo, WkT, D, D);
    transpose_cast<<<dim3(D/32,   D/32),   tb, 0, stream>>>(Wv + wo, WvT, D, D);
    transpose_cast<<<dim3(D/32,   D/32),   tb, 0, stream>>>(Wo + wo, WoT, D, D);
    transpose_cast<<<dim3(DFF/32, D/32),   tb, 0, stream>>>(W1 + wf, W1T, D, DFF);
    transpose_cast<<<dim3(D/32,   DFF/32), tb, 0, stream>>>(W2 + wf, W2T, DFF, D);

    gemm_bt<1,0,0><<<gDD, 256, 0, stream>>>(hb, D, WqT, qb, D, nullptr, D);
    gemm_bt<1,0,0><<<gDD, 256, 0, stream>>>(hb, D, WkT, kb, D, nullptr, D);
    gemm_bt<1,0,0><<<gDD, 256, 0, stream>>>(hb, D, WvT, vb, D, nullptr, D);
    attn_kernel<<<BATCH*NH, 256, 0, stream>>>(qb, kb, vb, rel + (size_t)l*NH*78*78, ctxb);
    gemm_bt<0,0,0><<<gDD, 256, 0, stream>>>(ctxb, D, WoT, tmp, D, nullptr, D);
    ln_kernel<<<ROWS, 256, 0, stream>>>(h, tmp, hb, ln1_g + l*D, ln1_b + l*D);
    gemm_bt<1,1,1><<<gDF, 256, 0, stream>>>(hb, D, W1T, gb, DFF, b1 + l*DFF, D);
    gemm_bt<0,1,0><<<gDD, 256, 0, stream>>>(gb, DFF, W2T, tmp, D, b2 + l*D, DFF);
    ln_kernel<<<ROWS, 256, 0, stream>>>(h, tmp, hb, ln2_g + l*D, ln2_b + l*D);
  }
  gemm_bt<0,1,0><<<dim3(BATCH/128, VOCAB/128), 256, 0, stream>>>(
      hb, TT * D, WouT, out, VOCAB, bout, D);
}

// Round 3
// 8135.500 us; speedup vs baseline: 1.1657x; 1.1657x over previous
//
#include <hip/hip_runtime.h>
#include <math.h>

typedef unsigned short u16;
typedef __attribute__((ext_vector_type(8))) short short8;
typedef __attribute__((ext_vector_type(4))) float f32x4;

#define LAYERS 8
#define D 1024
#define NH 16
#define DKH 64
#define DFF 4096
#define SEQ 66
#define TT 67
#define BATCH 256
#define ROWS (BATCH*TT)   /* 17152 = 134*128 */
#define VOCAB 4096
#define TP 80             /* T padded to 5x16 */
#define KP 96             /* PV K-dim padded to 3x32 */

__device__ __forceinline__ float bf2f(u16 v){
  unsigned int u = ((unsigned int)v) << 16;
  return __builtin_bit_cast(float, u);
}
__device__ __forceinline__ u16 f2bf(float f){
  unsigned int u = __builtin_bit_cast(unsigned int, f);
  u += 0x7FFFu + ((u >> 16) & 1u);
  return (u16)(u >> 16);
}

// ---------------- transpose + cast f32 -> bf16 ----------------
__global__ void transpose_cast(const float* __restrict__ src, u16* __restrict__ dst,
                               int R, int C){
  __shared__ float tile[32][33];
  const int c0 = blockIdx.x * 32, r0 = blockIdx.y * 32;
  const int tx = threadIdx.x, ty = threadIdx.y;
  #pragma unroll
  for (int i = 0; i < 32; i += 8)
    tile[ty + i][tx] = src[(size_t)(r0 + ty + i) * C + (c0 + tx)];
  __syncthreads();
  #pragma unroll
  for (int i = 0; i < 32; i += 8)
    dst[(size_t)(c0 + ty + i) * R + (r0 + tx)] = f2bf(tile[tx][ty + i]);
}

// ---------------- embedding + positional encoding ----------------
__global__ void embed_kernel(const int* __restrict__ x, const float* __restrict__ emb,
                             const float* __restrict__ pool, float* __restrict__ h,
                             u16* __restrict__ hb){
  const int row = blockIdx.x;
  const int b = row / TT, t = row % TT;
  const int d0 = threadIdx.x * 4;
  float v[4];
  if (t == 0){
    const float4 p4 = *(const float4*)&pool[d0];
    v[0] = p4.x; v[1] = p4.y; v[2] = p4.z; v[3] = p4.w;
  } else {
    const int id = x[b * SEQ + (t - 1)];
    const float4 e4 = *(const float4*)&emb[(size_t)id * D + d0];
    v[0] = e4.x * 32.f; v[1] = e4.y * 32.f; v[2] = e4.z * 32.f; v[3] = e4.w * 32.f;
  }
  const float c = -logf(10000.f) / (float)D;
  float o[4];
  #pragma unroll
  for (int j = 0; j < 4; j++){
    const int d = d0 + j;
    const int p = d >> 1;
    const float freq = expf((float)(2 * p) * c);
    const float ang = (float)t * freq;
    const float pe = (d & 1) ? cosf(ang) : sinf(ang);
    o[j] = v[j] + pe;
  }
  *(float4*)&h[(size_t)row * D + d0] = make_float4(o[0], o[1], o[2], o[3]);
  const unsigned int lo = (unsigned)f2bf(o[0]) | ((unsigned)f2bf(o[1]) << 16);
  const unsigned int hi = (unsigned)f2bf(o[2]) | ((unsigned)f2bf(o[3]) << 16);
  *(uint2*)&hb[(size_t)row * D + d0] = make_uint2(lo, hi);
}

// ---------------- fused residual + LayerNorm ----------------
__global__ void ln_kernel(float* __restrict__ h, const float* __restrict__ res,
                          u16* __restrict__ hb, const float* __restrict__ g,
                          const float* __restrict__ bta){
  const int row = blockIdx.x;
  const int tid = threadIdx.x;
  const size_t off = (size_t)row * D + tid * 4;
  const float4 a = *(const float4*)&h[off];
  const float4 r4 = *(const float4*)&res[off];
  const float s0 = a.x + r4.x, s1 = a.y + r4.y, s2 = a.z + r4.z, s3 = a.w + r4.w;
  float sum = s0 + s1 + s2 + s3;
  float sq = s0*s0 + s1*s1 + s2*s2 + s3*s3;
  #pragma unroll
  for (int m = 32; m >= 1; m >>= 1){ sum += __shfl_xor(sum, m); sq += __shfl_xor(sq, m); }
  __shared__ float red[2][4];
  const int w = tid >> 6;
  if ((tid & 63) == 0){ red[0][w] = sum; red[1][w] = sq; }
  __syncthreads();
  sum = red[0][0] + red[0][1] + red[0][2] + red[0][3];
  sq  = red[1][0] + red[1][1] + red[1][2] + red[1][3];
  const float mean = sum * (1.f / D);
  const float var = sq * (1.f / D) - mean * mean;
  const float rs = rsqrtf(var + 1e-5f);
  const float4 gv = *(const float4*)&g[tid * 4];
  const float4 bv = *(const float4*)&bta[tid * 4];
  const float o0 = (s0 - mean) * rs * gv.x + bv.x;
  const float o1 = (s1 - mean) * rs * gv.y + bv.y;
  const float o2 = (s2 - mean) * rs * gv.z + bv.z;
  const float o3 = (s3 - mean) * rs * gv.w + bv.w;
  *(float4*)&h[off] = make_float4(o0, o1, o2, o3);
  const unsigned int lo = (unsigned)f2bf(o0) | ((unsigned)f2bf(o1) << 16);
  const unsigned int hi = (unsigned)f2bf(o2) | ((unsigned)f2bf(o3) << 16);
  *(uint2*)&hb[off] = make_uint2(lo, hi);
}

// ---------------- MFMA attention: one block (4 waves) per (batch, head) ----------------
// frag-linear LDS layout: elem (row r, k-group g, e) at (g*NRpad + r)*8 + e
__global__ __launch_bounds__(256) void attn_kernel(const u16* __restrict__ qb,
    const u16* __restrict__ kb, const u16* __restrict__ vb,
    const float* __restrict__ rel, u16* __restrict__ ctxb){
  __shared__ u16 Qf[8 * 81 * 8];    // 80 rows (pad 81), K=64 -> 8 groups
  __shared__ u16 Kf[8 * 81 * 8];
  __shared__ u16 Vf[12 * 65 * 8];   // V^T: 64 n-rows (pad 65), K=96 -> 12 groups
  __shared__ u16 Pf[12 * 81 * 8];   // P: 80 rows (pad 81), K=96
  __shared__ float Ss[TP][84];
  const int bh = blockIdx.x;
  const int b = bh >> 4, hh = bh & 15;
  const int tid = threadIdx.x, w = tid >> 6, l = tid & 63;
  const size_t rowbase = (size_t)(b * TT) * D + hh * DKH;

  // ---- stage Q, K (rows >= 67 zeroed), V^T (keys >= 67 zeroed) ----
  {
    const int r0 = tid >> 4, c4 = (tid & 15) * 4;
    const int g = c4 >> 3, e = c4 & 7;
    for (int r = r0; r < TP; r += 16){
      uint2 q2 = make_uint2(0u, 0u), k2 = make_uint2(0u, 0u);
      if (r < TT){
        q2 = *(const uint2*)&qb[rowbase + (size_t)r * D + c4];
        k2 = *(const uint2*)&kb[rowbase + (size_t)r * D + c4];
      }
      *(uint2*)&Qf[(g * 81 + r) * 8 + e] = q2;
      *(uint2*)&Kf[(g * 81 + r) * 8 + e] = k2;
    }
    for (int j = r0; j < KP; j += 16){
      u16 v4[4] = {0, 0, 0, 0};
      if (j < TT) *(uint2*)v4 = *(const uint2*)&vb[rowbase + (size_t)j * D + c4];
      const int gg = j >> 3, ee = j & 7;
      #pragma unroll
      for (int d = 0; d < 4; d++)
        Vf[(gg * 65 + (c4 + d)) * 8 + ee] = v4[d];
    }
  }
  __syncthreads();

  const int fr = l & 15, gg = l >> 4;
  // ---- S = Q K^T * scale + rel_bias ----
  for (int p = w; p < 25; p += 4){
    const int rt = p / 5, ct = p % 5;
    f32x4 acc = {};
    #pragma unroll
    for (int kk = 0; kk < 2; kk++){
      const short8 a  = *(const short8*)&Qf[((kk * 4 + gg) * 81 + rt * 16 + fr) * 8];
      const short8 bf = *(const short8*)&Kf[((kk * 4 + gg) * 81 + ct * 16 + fr) * 8];
      acc = __builtin_amdgcn_mfma_f32_16x16x32_bf16(a, bf, acc, 0, 0, 0);
    }
    const int col = ct * 16 + fr;
    #pragma unroll
    for (int r = 0; r < 4; r++){
      const int row = rt * 16 + gg * 4 + r;
      float sv = -1e30f;
      if (row < TT && col < TT)
        sv = acc[r] * 0.125f + rel[((size_t)hh * 78 + row) * 78 + col];
      Ss[row][col] = sv;
    }
  }
  __syncthreads();

  // ---- row softmax -> P (bf16 frag-linear; cols>=67 underflow to 0, 80..95 zeroed) ----
  for (int row = w; row < TP; row += 4){
    const float s1 = Ss[row][l];
    const float s2 = (l < 16) ? Ss[row][64 + l] : -1e30f;
    float mx = fmaxf(s1, s2);
    #pragma unroll
    for (int m = 32; m >= 1; m >>= 1) mx = fmaxf(mx, __shfl_xor(mx, m));
    const float e1 = __expf(s1 - mx);
    const float e2 = (l < 16) ? __expf(s2 - mx) : 0.f;
    float sum = e1 + e2;
    #pragma unroll
    for (int m = 32; m >= 1; m >>= 1) sum += __shfl_xor(sum, m);
    const float inv = 1.f / sum;
    Pf[((l >> 3) * 81 + row) * 8 + (l & 7)] = f2bf(e1 * inv);
    if (l < 16){
      Pf[((8  + (l >> 3)) * 81 + row) * 8 + (l & 7)] = f2bf(e2 * inv);
      Pf[((10 + (l >> 3)) * 81 + row) * 8 + (l & 7)] = 0;
    }
  }
  __syncthreads();

  // ---- ctx = P V ----
  for (int p = w; p < 20; p += 4){
    const int rt = p >> 2, ct = p & 3;
    f32x4 acc = {};
    #pragma unroll
    for (int kk = 0; kk < 3; kk++){
      const short8 a  = *(const short8*)&Pf[((kk * 4 + gg) * 81 + rt * 16 + fr) * 8];
      const short8 bf = *(const short8*)&Vf[((kk * 4 + gg) * 65 + ct * 16 + fr) * 8];
      acc = __builtin_amdgcn_mfma_f32_16x16x32_bf16(a, bf, acc, 0, 0, 0);
    }
    #pragma unroll
    for (int r = 0; r < 4; r++){
      const int row = rt * 16 + gg * 4 + r;
      if (row < TT)
        ctxb[rowbase + (size_t)row * D + ct * 16 + fr] = f2bf(acc[r]);
    }
  }
}

// ---------------- bf16 MFMA GEMM (reg-staged): C = A @ Bt^T (+bias)(+gelu) ----------------
template<int OBF16, int BIAS, int GELU>
__global__ __launch_bounds__(256, 2) void gemm_bt(
    const u16* __restrict__ A, int lda,
    const u16* __restrict__ Bt,
    void* __restrict__ Cv, int ldc,
    const float* __restrict__ bias, int K)
{
  __shared__ u16 As[128 * 32];
  __shared__ u16 Bs[128 * 32];
  const int m0 = blockIdx.x * 128, n0 = blockIdx.y * 128;
  const int tid = threadIdx.x;
  const int l = tid & 63, w = tid >> 6;
  const int wr = w >> 1, wc = w & 1;
  const int srow = tid >> 2;
  const int sseg = (tid & 3) * 8;
  const u16* gA0 = A + (size_t)(m0 + srow) * lda + sseg;
  const u16* gA1 = A + (size_t)(m0 + 64 + srow) * lda + sseg;
  const u16* gB0 = Bt + (size_t)(n0 + srow) * K + sseg;
  const u16* gB1 = Bt + (size_t)(n0 + 64 + srow) * K + sseg;
  u16* sA0 = &As[srow * 32 + sseg];
  u16* sA1 = &As[(64 + srow) * 32 + sseg];
  u16* sB0 = &Bs[srow * 32 + sseg];
  u16* sB1 = &Bs[(64 + srow) * 32 + sseg];
  f32x4 acc[4][4] = {};
  const int fr = l & 15, kg = (l >> 4) * 8;
  for (int kt = 0; kt < K; kt += 32){
    const short8 a0 = *(const short8*)(gA0 + kt);
    const short8 a1 = *(const short8*)(gA1 + kt);
    const short8 b0 = *(const short8*)(gB0 + kt);
    const short8 b1 = *(const short8*)(gB1 + kt);
    __syncthreads();
    *(short8*)sA0 = a0; *(short8*)sA1 = a1;
    *(short8*)sB0 = b0; *(short8*)sB1 = b1;
    __syncthreads();
    short8 af[4], bf[4];
    #pragma unroll
    for (int i = 0; i < 4; i++){
      af[i] = *(const short8*)&As[(wr * 64 + i * 16 + fr) * 32 + kg];
      bf[i] = *(const short8*)&Bs[(wc * 64 + i * 16 + fr) * 32 + kg];
    }
    #pragma unroll
    for (int i = 0; i < 4; i++)
      #pragma unroll
      for (int j = 0; j < 4; j++)
        acc[i][j] = __builtin_amdgcn_mfma_f32_16x16x32_bf16(af[i], bf[j], acc[i][j], 0, 0, 0);
  }
  const int rg = (l >> 4) * 4;
  #pragma unroll
  for (int i = 0; i < 4; i++){
    #pragma unroll
    for (int j = 0; j < 4; j++){
      const int col = n0 + wc * 64 + j * 16 + fr;
      const float bv = BIAS ? bias[col] : 0.f;
      #pragma unroll
      for (int r = 0; r < 4; r++){
        const int row = m0 + wr * 64 + i * 16 + rg + r;
        float xv = acc[i][j][r] + bv;
        if (GELU) xv = 0.5f * xv * (1.f + erff(xv * 0.70710678118f));
        if (OBF16) ((u16*)Cv)[(size_t)row * ldc + col] = f2bf(xv);
        else       ((float*)Cv)[(size_t)row * ldc + col] = xv;
      }
    }
  }
}

extern "C" void kernel_launch(void* const* d_in, const int* in_sizes, int n_in,
                              void* d_out, int out_size, void* d_ws, size_t ws_size,
                              hipStream_t stream) {
  const int*   x       = (const int*)  d_in[0];
  const float* emb     = (const float*)d_in[1];
  const float* pool    = (const float*)d_in[2];
  const float* Wq      = (const float*)d_in[3];
  const float* Wk      = (const float*)d_in[4];
  const float* Wv      = (const float*)d_in[5];
  const float* Wo      = (const float*)d_in[6];
  const float* rel     = (const float*)d_in[7];
  const float* ln1_g   = (const float*)d_in[8];
  const float* ln1_b   = (const float*)d_in[9];
  const float* ln2_g   = (const float*)d_in[10];
  const float* ln2_b   = (const float*)d_in[11];
  const float* W1      = (const float*)d_in[12];
  const float* b1      = (const float*)d_in[13];
  const float* W2      = (const float*)d_in[14];
  const float* b2      = (const float*)d_in[15];
  const float* Wout    = (const float*)d_in[16];
  const float* bout    = (const float*)d_in[17];
  float* out = (float*)d_out;

  const size_t SZ_WDD  = (size_t)D * D * 2;
  const size_t SZ_WDF  = (size_t)D * DFF * 2;
  const size_t SZ_H    = (size_t)ROWS * D * 4;
  const size_t SZ_HB   = (size_t)ROWS * D * 2;
  const size_t need = 4*SZ_WDD + 3*SZ_WDF + SZ_H + SZ_HB + 4*SZ_HB + SZ_H;
  if (ws_size < need) return;

  char* p = (char*)d_ws;
  u16* WqT  = (u16*)p; p += SZ_WDD;
  u16* WkT  = (u16*)p; p += SZ_WDD;
  u16* WvT  = (u16*)p; p += SZ_WDD;
  u16* WoT  = (u16*)p; p += SZ_WDD;
  u16* W1T  = (u16*)p; p += SZ_WDF;
  u16* W2T  = (u16*)p; p += SZ_WDF;
  u16* WouT = (u16*)p; p += SZ_WDF;
  float* h  = (float*)p; p += SZ_H;
  u16* hb   = (u16*)p; p += SZ_HB;
  u16* qb   = (u16*)p; p += SZ_HB;
  u16* kb   = (u16*)p; p += SZ_HB;
  u16* vb   = (u16*)p; p += SZ_HB;
  u16* ctxb = (u16*)p; p += SZ_HB;
  u16* gb   = qb;
  float* tmp = (float*)p; p += SZ_H;

  dim3 tb(32, 8);
  transpose_cast<<<dim3(VOCAB/32, D/32), tb, 0, stream>>>(Wout, WouT, D, VOCAB);
  embed_kernel<<<ROWS, 256, 0, stream>>>(x, emb, pool, h, hb);

  const dim3 gDD(ROWS/128, D/128);
  const dim3 gDF(ROWS/128, DFF/128);
  for (int l = 0; l < LAYERS; ++l){
    const size_t wo = (size_t)l * D * D;
    const size_t wf = (size_t)l * D * DFF;
    transpose_cast<<<dim3(D/32,   D/32),   tb, 0, stream>>>(Wq + wo, WqT, D, D);
    transpose_cast<<<dim3(D/32,   D/32),   tb, 0, stream>>>(Wk + wo, WkT, D, D);
    transpose_cast<<<dim3(D/32,   D/32),   tb, 0, stream>>>(Wv + wo, WvT, D, D);
    transpose_cast<<<dim3(D/32,   D/32),   tb, 0, stream>>>(Wo + wo, WoT, D, D);
    transpose_cast<<<dim3(DFF/32, D/32),   tb, 0, stream>>>(W1 + wf, W1T, D, DFF);
    transpose_cast<<<dim3(D/32,   DFF/32), tb, 0, stream>>>(W2 + wf, W2T, DFF, D);

    gemm_bt<1,0,0><<<gDD, 256, 0, stream>>>(hb, D, WqT, qb, D, nullptr, D);
    gemm_bt<1,0,0><<<gDD, 256, 0, stream>>>(hb, D, WkT, kb, D, nullptr, D);
    gemm_bt<1,0,0><<<gDD, 256, 0, stream>>>(hb, D, WvT, vb, D, nullptr, D);
    attn_kernel<<<BATCH*NH, 256, 0, stream>>>(qb, kb, vb, rel + (size_t)l*NH*78*78, ctxb);
    gemm_bt<0,0,0><<<gDD, 256, 0, stream>>>(ctxb, D, WoT, tmp, D, nullptr, D);
    ln_kernel<<<ROWS, 256, 0, stream>>>(h, tmp, hb, ln1_g + l*D, ln1_b + l*D);
    gemm_bt<1,1,1><<<gDF, 256, 0, stream>>>(hb, D, W1T, gb, DFF, b1 + l*DFF, D);
    gemm_bt<0,1,0><<<gDD, 256, 0, stream>>>(gb, DFF, W2T, tmp, D, b2 + l*D, DFF);
    ln_kernel<<<ROWS, 256, 0, stream>>>(h, tmp, hb, ln2_g + l*D, ln2_b + l*D);
  }
  gemm_bt<0,1,0><<<dim3(BATCH/128, VOCAB/128), 256, 0, stream>>>(
      hb, TT * D, WouT, out, VOCAB, bout, D);
}

// Round 4
// 8027.488 us; speedup vs baseline: 1.1814x; 1.0135x over previous
//
#include <hip/hip_runtime.h>
#include <math.h>

typedef unsigned short u16;
typedef __attribute__((ext_vector_type(8))) short short8;
typedef __attribute__((ext_vector_type(4))) float f32x4;

#define LAYERS 8
#define D 1024
#define NH 16
#define DKH 64
#define DFF 4096
#define SEQ 66
#define TT 67
#define BATCH 256
#define ROWS (BATCH*TT)   /* 17152 = 134*128 */
#define VOCAB 4096
#define TP 80
#define KP 96

__device__ __forceinline__ float bf2f(u16 v){
  unsigned int u = ((unsigned int)v) << 16;
  return __builtin_bit_cast(float, u);
}
__device__ __forceinline__ u16 f2bf(float f){
  unsigned int u = __builtin_bit_cast(unsigned int, f);
  u += 0x7FFFu + ((u >> 16) & 1u);
  return (u16)(u >> 16);
}
__device__ __forceinline__ void gload16(const u16* g, u16* l){
  __builtin_amdgcn_global_load_lds((const __attribute__((address_space(1))) void*)g,
                                   (__attribute__((address_space(3))) void*)l, 16, 0, 0);
}

// ---------------- transpose + cast f32 -> bf16 ----------------
__global__ void transpose_cast(const float* __restrict__ src, u16* __restrict__ dst,
                               int R, int C){
  __shared__ float tile[32][33];
  const int c0 = blockIdx.x * 32, r0 = blockIdx.y * 32;
  const int tx = threadIdx.x, ty = threadIdx.y;
  #pragma unroll
  for (int i = 0; i < 32; i += 8)
    tile[ty + i][tx] = src[(size_t)(r0 + ty + i) * C + (c0 + tx)];
  __syncthreads();
  #pragma unroll
  for (int i = 0; i < 32; i += 8)
    dst[(size_t)(c0 + ty + i) * R + (r0 + tx)] = f2bf(tile[tx][ty + i]);
}

// ---------------- embedding + positional encoding ----------------
__global__ void embed_kernel(const int* __restrict__ x, const float* __restrict__ emb,
                             const float* __restrict__ pool, float* __restrict__ h,
                             u16* __restrict__ hb){
  const int row = blockIdx.x;
  const int b = row / TT, t = row % TT;
  const int d0 = threadIdx.x * 4;
  float v[4];
  if (t == 0){
    const float4 p4 = *(const float4*)&pool[d0];
    v[0] = p4.x; v[1] = p4.y; v[2] = p4.z; v[3] = p4.w;
  } else {
    const int id = x[b * SEQ + (t - 1)];
    const float4 e4 = *(const float4*)&emb[(size_t)id * D + d0];
    v[0] = e4.x * 32.f; v[1] = e4.y * 32.f; v[2] = e4.z * 32.f; v[3] = e4.w * 32.f;
  }
  const float c = -logf(10000.f) / (float)D;
  float o[4];
  #pragma unroll
  for (int j = 0; j < 4; j++){
    const int d = d0 + j;
    const int p = d >> 1;
    const float freq = expf((float)(2 * p) * c);
    const float ang = (float)t * freq;
    const float pe = (d & 1) ? cosf(ang) : sinf(ang);
    o[j] = v[j] + pe;
  }
  *(float4*)&h[(size_t)row * D + d0] = make_float4(o[0], o[1], o[2], o[3]);
  const unsigned int lo = (unsigned)f2bf(o[0]) | ((unsigned)f2bf(o[1]) << 16);
  const unsigned int hi = (unsigned)f2bf(o[2]) | ((unsigned)f2bf(o[3]) << 16);
  *(uint2*)&hb[(size_t)row * D + d0] = make_uint2(lo, hi);
}

// ---------------- fused residual + LayerNorm ----------------
__global__ void ln_kernel(float* __restrict__ h, const float* __restrict__ res,
                          u16* __restrict__ hb, const float* __restrict__ g,
                          const float* __restrict__ bta){
  const int row = blockIdx.x;
  const int tid = threadIdx.x;
  const size_t off = (size_t)row * D + tid * 4;
  const float4 a = *(const float4*)&h[off];
  const float4 r4 = *(const float4*)&res[off];
  const float s0 = a.x + r4.x, s1 = a.y + r4.y, s2 = a.z + r4.z, s3 = a.w + r4.w;
  float sum = s0 + s1 + s2 + s3;
  float sq = s0*s0 + s1*s1 + s2*s2 + s3*s3;
  #pragma unroll
  for (int m = 32; m >= 1; m >>= 1){ sum += __shfl_xor(sum, m); sq += __shfl_xor(sq, m); }
  __shared__ float red[2][4];
  const int w = tid >> 6;
  if ((tid & 63) == 0){ red[0][w] = sum; red[1][w] = sq; }
  __syncthreads();
  sum = red[0][0] + red[0][1] + red[0][2] + red[0][3];
  sq  = red[1][0] + red[1][1] + red[1][2] + red[1][3];
  const float mean = sum * (1.f / D);
  const float var = sq * (1.f / D) - mean * mean;
  const float rs = rsqrtf(var + 1e-5f);
  const float4 gv = *(const float4*)&g[tid * 4];
  const float4 bv = *(const float4*)&bta[tid * 4];
  const float o0 = (s0 - mean) * rs * gv.x + bv.x;
  const float o1 = (s1 - mean) * rs * gv.y + bv.y;
  const float o2 = (s2 - mean) * rs * gv.z + bv.z;
  const float o3 = (s3 - mean) * rs * gv.w + bv.w;
  *(float4*)&h[off] = make_float4(o0, o1, o2, o3);
  const unsigned int lo = (unsigned)f2bf(o0) | ((unsigned)f2bf(o1) << 16);
  const unsigned int hi = (unsigned)f2bf(o2) | ((unsigned)f2bf(o3) << 16);
  *(uint2*)&hb[off] = make_uint2(lo, hi);
}

// ---------------- MFMA attention: one block (4 waves) per (batch, head) ----------------
__global__ __launch_bounds__(256) void attn_kernel(const u16* __restrict__ qb,
    const u16* __restrict__ kb, const u16* __restrict__ vb,
    const float* __restrict__ rel, u16* __restrict__ ctxb){
  __shared__ u16 Qf[8 * 81 * 8];
  __shared__ u16 Kf[8 * 81 * 8];
  __shared__ u16 Vf[12 * 65 * 8];
  __shared__ u16 Pf[12 * 81 * 8];
  __shared__ float Ss[TP][84];
  const int bh = blockIdx.x;
  const int b = bh >> 4, hh = bh & 15;
  const int tid = threadIdx.x, w = tid >> 6, l = tid & 63;
  const size_t rowbase = (size_t)(b * TT) * D + hh * DKH;

  {
    const int r0 = tid >> 4, c4 = (tid & 15) * 4;
    const int g = c4 >> 3, e = c4 & 7;
    for (int r = r0; r < TP; r += 16){
      uint2 q2 = make_uint2(0u, 0u), k2 = make_uint2(0u, 0u);
      if (r < TT){
        q2 = *(const uint2*)&qb[rowbase + (size_t)r * D + c4];
        k2 = *(const uint2*)&kb[rowbase + (size_t)r * D + c4];
      }
      *(uint2*)&Qf[(g * 81 + r) * 8 + e] = q2;
      *(uint2*)&Kf[(g * 81 + r) * 8 + e] = k2;
    }
    for (int j = r0; j < KP; j += 16){
      u16 v4[4] = {0, 0, 0, 0};
      if (j < TT) *(uint2*)v4 = *(const uint2*)&vb[rowbase + (size_t)j * D + c4];
      const int gg = j >> 3, ee = j & 7;
      #pragma unroll
      for (int d = 0; d < 4; d++)
        Vf[(gg * 65 + (c4 + d)) * 8 + ee] = v4[d];
    }
  }
  __syncthreads();

  const int fr = l & 15, gg = l >> 4;
  for (int p = w; p < 25; p += 4){
    const int rt = p / 5, ct = p % 5;
    f32x4 acc = {};
    #pragma unroll
    for (int kk = 0; kk < 2; kk++){
      const short8 a  = *(const short8*)&Qf[((kk * 4 + gg) * 81 + rt * 16 + fr) * 8];
      const short8 bf = *(const short8*)&Kf[((kk * 4 + gg) * 81 + ct * 16 + fr) * 8];
      acc = __builtin_amdgcn_mfma_f32_16x16x32_bf16(a, bf, acc, 0, 0, 0);
    }
    const int col = ct * 16 + fr;
    #pragma unroll
    for (int r = 0; r < 4; r++){
      const int row = rt * 16 + gg * 4 + r;
      float sv = -1e30f;
      if (row < TT && col < TT)
        sv = acc[r] * 0.125f + rel[((size_t)hh * 78 + row) * 78 + col];
      Ss[row][col] = sv;
    }
  }
  __syncthreads();

  for (int row = w; row < TP; row += 4){
    const float s1 = Ss[row][l];
    const float s2 = (l < 16) ? Ss[row][64 + l] : -1e30f;
    float mx = fmaxf(s1, s2);
    #pragma unroll
    for (int m = 32; m >= 1; m >>= 1) mx = fmaxf(mx, __shfl_xor(mx, m));
    const float e1 = __expf(s1 - mx);
    const float e2 = (l < 16) ? __expf(s2 - mx) : 0.f;
    float sum = e1 + e2;
    #pragma unroll
    for (int m = 32; m >= 1; m >>= 1) sum += __shfl_xor(sum, m);
    const float inv = 1.f / sum;
    Pf[((l >> 3) * 81 + row) * 8 + (l & 7)] = f2bf(e1 * inv);
    if (l < 16){
      Pf[((8  + (l >> 3)) * 81 + row) * 8 + (l & 7)] = f2bf(e2 * inv);
      Pf[((10 + (l >> 3)) * 81 + row) * 8 + (l & 7)] = 0;
    }
  }
  __syncthreads();

  for (int p = w; p < 20; p += 4){
    const int rt = p >> 2, ct = p & 3;
    f32x4 acc = {};
    #pragma unroll
    for (int kk = 0; kk < 3; kk++){
      const short8 a  = *(const short8*)&Pf[((kk * 4 + gg) * 81 + rt * 16 + fr) * 8];
      const short8 bf = *(const short8*)&Vf[((kk * 4 + gg) * 65 + ct * 16 + fr) * 8];
      acc = __builtin_amdgcn_mfma_f32_16x16x32_bf16(a, bf, acc, 0, 0, 0);
    }
    #pragma unroll
    for (int r = 0; r < 4; r++){
      const int row = rt * 16 + gg * 4 + r;
      if (row < TT)
        ctxb[rowbase + (size_t)row * D + ct * 16 + fr] = f2bf(acc[r]);
    }
  }
}

// ---------------- bf16 MFMA GEMM (global_load_lds staged, m97 structure) ----------------
// C = A @ Bt^T (+bias)(+gelu); A: M x K bf16 (lda), Bt: N x K bf16, C: M x N
template<int OBF16, int BIAS, int GELU>
__global__ __launch_bounds__(256, 2) void gemm_bt(
    const u16* __restrict__ A, int lda,
    const u16* __restrict__ Bt,
    void* __restrict__ Cv, int ldc,
    const float* __restrict__ bias, int K)
{
  __shared__ u16 As[128 * 32];
  __shared__ u16 Bs[128 * 32];
  const int m0 = blockIdx.x * 128, n0 = blockIdx.y * 128;
  const int tid = threadIdx.x;
  const int l = tid & 63, w = tid >> 6;
  const int wr = w >> 1, wc = w & 1;
  f32x4 acc[4][4] = {};
  // staging: wave w covers rows [w*32, w*32+32); lane l -> row +(l>>2), seg (l&3)*8
  // LDS byte offset within wave region = l*16 (linear) -> gload_lds compatible
  const int lr = l >> 2;
  const int lseg = (l & 3) * 8;
  u16* aB0 = &As[(w * 32) * 32];
  u16* aB1 = &As[(w * 32 + 16) * 32];
  u16* bB0 = &Bs[(w * 32) * 32];
  u16* bB1 = &Bs[(w * 32 + 16) * 32];
  const u16* ga0 = A + (size_t)(m0 + w * 32 + lr) * lda + lseg;
  const u16* ga1 = A + (size_t)(m0 + w * 32 + 16 + lr) * lda + lseg;
  const u16* gb0 = Bt + (size_t)(n0 + w * 32 + lr) * K + lseg;
  const u16* gb1 = Bt + (size_t)(n0 + w * 32 + 16 + lr) * K + lseg;
  const int fr = l & 15, kg = (l >> 4) * 8;
  for (int kt = 0; kt < K; kt += 32){
    __syncthreads();                 // previous tile fully consumed
    gload16(ga0 + kt, aB0);
    gload16(ga1 + kt, aB1);
    gload16(gb0 + kt, bB0);
    gload16(gb1 + kt, bB1);
    __syncthreads();                 // vmcnt(0) drained by barrier semantics
    short8 af[4], bf[4];
    #pragma unroll
    for (int i = 0; i < 4; i++){
      af[i] = *(const short8*)&As[(wr * 64 + i * 16 + fr) * 32 + kg];
      bf[i] = *(const short8*)&Bs[(wc * 64 + i * 16 + fr) * 32 + kg];
    }
    #pragma unroll
    for (int i = 0; i < 4; i++)
      #pragma unroll
      for (int j = 0; j < 4; j++)
        acc[i][j] = __builtin_amdgcn_mfma_f32_16x16x32_bf16(af[i], bf[j], acc[i][j], 0, 0, 0);
  }
  const int rg = (l >> 4) * 4;
  #pragma unroll
  for (int i = 0; i < 4; i++){
    #pragma unroll
    for (int j = 0; j < 4; j++){
      const int col = n0 + wc * 64 + j * 16 + fr;
      const float bv = BIAS ? bias[col] : 0.f;
      #pragma unroll
      for (int r = 0; r < 4; r++){
        const int row = m0 + wr * 64 + i * 16 + rg + r;
        float xv = acc[i][j][r] + bv;
        if (GELU) xv = 0.5f * xv * (1.f + erff(xv * 0.70710678118f));
        if (OBF16) ((u16*)Cv)[(size_t)row * ldc + col] = f2bf(xv);
        else       ((float*)Cv)[(size_t)row * ldc + col] = xv;
      }
    }
  }
}

extern "C" void kernel_launch(void* const* d_in, const int* in_sizes, int n_in,
                              void* d_out, int out_size, void* d_ws, size_t ws_size,
                              hipStream_t stream) {
  const int*   x       = (const int*)  d_in[0];
  const float* emb     = (const float*)d_in[1];
  const float* pool    = (const float*)d_in[2];
  const float* Wq      = (const float*)d_in[3];
  const float* Wk      = (const float*)d_in[4];
  const float* Wv      = (const float*)d_in[5];
  const float* Wo      = (const float*)d_in[6];
  const float* rel     = (const float*)d_in[7];
  const float* ln1_g   = (const float*)d_in[8];
  const float* ln1_b   = (const float*)d_in[9];
  const float* ln2_g   = (const float*)d_in[10];
  const float* ln2_b   = (const float*)d_in[11];
  const float* W1      = (const float*)d_in[12];
  const float* b1      = (const float*)d_in[13];
  const float* W2      = (const float*)d_in[14];
  const float* b2      = (const float*)d_in[15];
  const float* Wout    = (const float*)d_in[16];
  const float* bout    = (const float*)d_in[17];
  float* out = (float*)d_out;

  const size_t SZ_WDD  = (size_t)D * D * 2;
  const size_t SZ_WDF  = (size_t)D * DFF * 2;
  const size_t SZ_H    = (size_t)ROWS * D * 4;
  const size_t SZ_HB   = (size_t)ROWS * D * 2;
  const size_t need = 4*SZ_WDD + 3*SZ_WDF + SZ_H + SZ_HB + 4*SZ_HB + SZ_H;
  if (ws_size < need) return;

  char* p = (char*)d_ws;
  u16* WqT  = (u16*)p; p += SZ_WDD;
  u16* WkT  = (u16*)p; p += SZ_WDD;
  u16* WvT  = (u16*)p; p += SZ_WDD;
  u16* WoT  = (u16*)p; p += SZ_WDD;
  u16* W1T  = (u16*)p; p += SZ_WDF;
  u16* W2T  = (u16*)p; p += SZ_WDF;
  u16* WouT = (u16*)p; p += SZ_WDF;
  float* h  = (float*)p; p += SZ_H;
  u16* hb   = (u16*)p; p += SZ_HB;
  u16* qb   = (u16*)p; p += SZ_HB;
  u16* kb   = (u16*)p; p += SZ_HB;
  u16* vb   = (u16*)p; p += SZ_HB;
  u16* ctxb = (u16*)p; p += SZ_HB;
  u16* gb   = qb;
  float* tmp = (float*)p; p += SZ_H;

  dim3 tb(32, 8);
  transpose_cast<<<dim3(VOCAB/32, D/32), tb, 0, stream>>>(Wout, WouT, D, VOCAB);
  embed_kernel<<<ROWS, 256, 0, stream>>>(x, emb, pool, h, hb);

  const dim3 gDD(ROWS/128, D/128);
  const dim3 gDF(ROWS/128, DFF/128);
  for (int l = 0; l < LAYERS; ++l){
    const size_t wo = (size_t)l * D * D;
    const size_t wf = (size_t)l * D * DFF;
    transpose_cast<<<dim3(D/32,   D/32),   tb, 0, stream>>>(Wq + wo, WqT, D, D);
    transpose_cast<<<dim3(D/32,   D/32),   tb, 0, stream>>>(Wk + wo, WkT, D, D);
    transpose_cast<<<dim3(D/32,   D/32),   tb, 0, stream>>>(Wv + wo, WvT, D, D);
    transpose_cast<<<dim3(D/32,   D/32),   tb, 0, stream>>>(Wo + wo, WoT, D, D);
    transpose_cast<<<dim3(DFF/32, D/32),   tb, 0, stream>>>(W1 + wf, W1T, D, DFF);
    transpose_cast<<<dim3(D/32,   DFF/32), tb, 0, stream>>>(W2 + wf, W2T, DFF, D);

    gemm_bt<1,0,0><<<gDD, 256, 0, stream>>>(hb, D, WqT, qb, D, nullptr, D);
    gemm_bt<1,0,0><<<gDD, 256, 0, stream>>>(hb, D, WkT, kb, D, nullptr, D);
    gemm_bt<1,0,0><<<gDD, 256, 0, stream>>>(hb, D, WvT, vb, D, nullptr, D);
    attn_kernel<<<BATCH*NH, 256, 0, stream>>>(qb, kb, vb, rel + (size_t)l*NH*78*78, ctxb);
    gemm_bt<0,0,0><<<gDD, 256, 0, stream>>>(ctxb, D, WoT, tmp, D, nullptr, D);
    ln_kernel<<<ROWS, 256, 0, stream>>>(h, tmp, hb, ln1_g + l*D, ln1_b + l*D);
    gemm_bt<1,1,1><<<gDF, 256, 0, stream>>>(hb, D, W1T, gb, DFF, b1 + l*DFF, D);
    gemm_bt<0,1,0><<<gDD, 256, 0, stream>>>(gb, DFF, W2T, tmp, D, b2 + l*D, DFF);
    ln_kernel<<<ROWS, 256, 0, stream>>>(h, tmp, hb, ln2_g + l*D, ln2_b + l*D);
  }
  gemm_bt<0,1,0><<<dim3(BATCH/128, VOCAB/128), 256, 0, stream>>>(
      hb, TT * D, WouT, out, VOCAB, bout, D);
}